// Round 13
// baseline (217.417 us; speedup 1.0000x reference)
//
#include <hip/hip_runtime.h>
#include <cstddef>
#include <cstdint>

// Shapes: B=4, M=16, T=256, D=128, H=8, CTX=16, L=2
static constexpr int D_ = 128;
static constexpr int NROW = 16384;               // B*M*T rows
static constexpr size_t S_ = (size_t)NROW * D_;  // elems per activation

typedef __attribute__((ext_vector_type(8))) short bf16x8;
typedef __attribute__((ext_vector_type(4))) float f32x4;
typedef __attribute__((ext_vector_type(16))) float f32x16;
typedef __attribute__((ext_vector_type(8))) unsigned short ushortx8;

__device__ __forceinline__ unsigned short f2bf(float f) {
  unsigned int u = __float_as_uint(f);
  u += 0x7fff + ((u >> 16) & 1);
  return (unsigned short)(u >> 16);
}
__device__ __forceinline__ float bf2f(unsigned short h) {
  return __uint_as_float(((unsigned int)h) << 16);
}
__device__ __forceinline__ unsigned int cvt_pk_bf16(float lo, float hi) {
  unsigned int r;
  asm volatile("v_cvt_pk_bf16_f32 %0, %1, %2" : "=v"(r) : "v"(lo), "v"(hi));
  return r;
}
__device__ __forceinline__ float wsum64(float s) {
#pragma unroll
  for (int off = 32; off >= 1; off >>= 1) s += __shfl_xor(s, off);
  return s;
}

// ---- prep: [0,192) wconv | [192,201) bconv | [201,4297) lnconv(x, layer-0) ----
__global__ __launch_bounds__(256) void prep_kernel(
    const float* __restrict__ X,
    const float* __restrict__ Wq, const float* __restrict__ Wk,
    const float* __restrict__ Wv, const float* __restrict__ Wo,
    const float* __restrict__ W1, const float* __restrict__ W2,
    const float* __restrict__ bq, const float* __restrict__ bk,
    const float* __restrict__ bv, const float* __restrict__ bo,
    const float* __restrict__ b1, const float* __restrict__ b2,
    const float* __restrict__ g, const float* __restrict__ b,
    unsigned short* __restrict__ Wb, float* __restrict__ Bs,
    unsigned short* __restrict__ Ab) {
  int bx = blockIdx.x;
  if (bx < 192) {
    size_t i = ((size_t)bx * 256 + threadIdx.x) * 8;
    int layer = i >= 196608;
    size_t o = i - (size_t)layer * 196608;
    const float* src; size_t off;
    if      (o < 16384)  { src = Wq + layer * 16384; off = o; }
    else if (o < 32768)  { src = Wk + layer * 16384; off = o - 16384; }
    else if (o < 49152)  { src = Wv + layer * 16384; off = o - 32768; }
    else if (o < 65536)  { src = Wo + layer * 16384; off = o - 49152; }
    else if (o < 131072) { src = W1 + layer * 65536; off = o - 65536; }
    else                 { src = W2 + layer * 65536; off = o - 131072; }
    ushortx8 r;
#pragma unroll
    for (int j = 0; j < 8; j++) r[j] = f2bf(src[off + j]);
    *(ushortx8*)(Wb + i) = r;
  } else if (bx < 201) {
    int tid = (bx - 192) * 256 + threadIdx.x;
    if (tid >= 2304) return;
    int layer = tid / 1152, o = tid % 1152;
    float v;
    if      (o < 128)  v = bq[layer * 128 + o];
    else if (o < 256)  v = bk[layer * 128 + o - 128];
    else if (o < 384)  v = bv[layer * 128 + o - 256];
    else if (o < 512)  v = bo[layer * 128 + o - 384];
    else if (o < 1024) v = b1[layer * 512 + o - 512];
    else               v = b2[layer * 128 + o - 1024];
    Bs[tid] = v;
  } else {
    int wid = threadIdx.x >> 6, lane = threadIdx.x & 63;
    int row = ((bx - 201) << 2) + wid;
    float2 xv = *(const float2*)(X + (size_t)row * D_ + lane * 2);
    float s = wsum64(xv.x + xv.y);
    float sq = wsum64(xv.x * xv.x + xv.y * xv.y);
    float mu = s * (1.0f / 128.0f);
    float var = sq * (1.0f / 128.0f) - mu * mu;
    float rstd = rsqrtf(var + 1e-6f);
    float2 gv = *(const float2*)(g + lane * 2);
    float2 bv2 = *(const float2*)(b + lane * 2);
    unsigned int lo = f2bf((xv.x - mu) * rstd * gv.x + bv2.x);
    unsigned int hi = f2bf((xv.y - mu) * rstd * gv.y + bv2.y);
    *(unsigned int*)(Ab + (size_t)row * D_ + lane * 2) = lo | (hi << 16);
  }
}

// ---- bf16 MFMA GEMM (QKV): 16-row blocks, 8 col-waves ----
template <int NT, int ROWW>
__global__ __launch_bounds__(512, 2) void gemm_kernel(
    const unsigned short* __restrict__ A, int lda,
    const unsigned short* __restrict__ W, int ldw,
    const float* __restrict__ bias,
    unsigned short* __restrict__ Cb, int K) {
  constexpr int COLW = 8 / ROWW;
  const int w = threadIdx.x >> 6;
  const int l = threadIdx.x & 63;
  const int rw = w / COLW, cw = w % COLW;
  const int r0 = blockIdx.x * (16 * ROWW) + rw * 16;
  const int c0 = cw * (NT * 16);
  const int lr = l & 15, lk = (l >> 4) * 8;
  f32x4 acc[NT] = {};
  const unsigned short* Ap = A + (size_t)(r0 + lr) * lda + lk;
  const unsigned short* Wp = W + (size_t)(c0 + lr) * ldw + lk;
  for (int kb = 0; kb < K; kb += 128) {
    bf16x8 aF[4];
    bf16x8 wF[4][NT];
#pragma unroll
    for (int kt = 0; kt < 4; ++kt) {
      int k0 = kb + kt * 32;
      aF[kt] = *(const bf16x8*)(Ap + k0);
#pragma unroll
      for (int n = 0; n < NT; ++n)
        wF[kt][n] = *(const bf16x8*)(Wp + (size_t)(n * 16) * ldw + k0);
    }
#pragma unroll
    for (int kt = 0; kt < 4; ++kt)
#pragma unroll
      for (int n = 0; n < NT; ++n)
        acc[n] = __builtin_amdgcn_mfma_f32_16x16x32_bf16(aF[kt], wF[kt][n], acc[n], 0, 0, 0);
  }
  const int rb = (l >> 4) * 4;
#pragma unroll
  for (int n = 0; n < NT; ++n) {
    int col = c0 + n * 16 + lr;
    float bval = bias[col];
    unsigned short* dst = Cb + (size_t)(col >> 7) * S_ + (col & 127);
#pragma unroll
    for (int j = 0; j < 4; ++j)
      dst[(size_t)(r0 + rb + j) * 128] = f2bf(acc[n][j] + bval);
  }
}

// ---- fused half-layer v4: 16-row blocks, grid 1024 (4 blocks/CU), 4 waves x 32 cols,
//      Mid double-buffered (1 barrier per chunk). TLP hides latency. ----
static constexpr int LDH = 136;
__global__ __launch_bounds__(256, 2) void ffn_kernel(
    const unsigned short* __restrict__ Abuf,
    const unsigned short* __restrict__ Wo_, const unsigned short* __restrict__ W1_,
    const unsigned short* __restrict__ W2_, const float* __restrict__ Bl,
    const float* __restrict__ rin,
    const float* __restrict__ ln2G, const float* __restrict__ ln2B,
    const float* __restrict__ lnxG, const float* __restrict__ lnxB,
    float* __restrict__ Yout, unsigned short* __restrict__ AbOut, int finalMode) {
  __shared__ unsigned short As[16][LDH];
  __shared__ unsigned short Hs[16][LDH];
  __shared__ unsigned short Mid[2][16][LDH];
  __shared__ float2 lnred[16][4];
  const int tid = threadIdx.x;
  const int w = tid >> 6, l = tid & 63;
  const int r0 = blockIdx.x * 16;
  const int lr = l & 15, lk = (l >> 4) * 8, rb = (l >> 4) * 4;
  const int cbase = w * 32;

  // residual prefetch (coalesced 64B segments)
  float rv[2][4];
#pragma unroll
  for (int n = 0; n < 2; ++n) {
    int col = cbase + n * 16 + lr;
#pragma unroll
    for (int j = 0; j < 4; ++j)
      rv[n][j] = rin[(size_t)(r0 + rb + j) * 128 + col];
  }
  // Wo fragments (block-unique, L2-hot)
  bf16x8 wof[4][2];
#pragma unroll
  for (int n = 0; n < 2; ++n) {
    int col = cbase + n * 16 + lr;
#pragma unroll
    for (int kt = 0; kt < 4; ++kt)
      wof[kt][n] = *(const bf16x8*)(Wo_ + (size_t)col * 128 + kt * 32 + lk);
  }
  // stage A (16 rows x 128 cols bf16): 1 ushortx8 per thread
  {
    int r = tid >> 4, c8 = (tid & 15) * 8;
    *(ushortx8*)&As[r][c8] = *(const ushortx8*)(Abuf + (size_t)(r0 + r) * 128 + c8);
  }
  __syncthreads();

  // ---- Phase 1: Wo (K=128) + bo + rin -> yreg ----
  f32x4 acc1[2] = {};
#pragma unroll
  for (int kt = 0; kt < 4; ++kt) {
    bf16x8 a = *(const bf16x8*)&As[lr][kt * 32 + lk];
#pragma unroll
    for (int n = 0; n < 2; ++n)
      acc1[n] = __builtin_amdgcn_mfma_f32_16x16x32_bf16(a, wof[kt][n], acc1[n], 0, 0, 0);
  }
  float yreg[2][4];
#pragma unroll
  for (int n = 0; n < 2; ++n) {
    float bval = Bl[384 + cbase + n * 16 + lr];
#pragma unroll
    for (int j = 0; j < 4; ++j)
      yreg[n][j] = acc1[n][j] + bval + rv[n][j];
  }
  // ---- Phase 2: LN2 -> Hs ----
  {
    float s[4], sq[4];
#pragma unroll
    for (int j = 0; j < 4; ++j) {
      s[j] = yreg[0][j] + yreg[1][j];
      sq[j] = yreg[0][j] * yreg[0][j] + yreg[1][j] * yreg[1][j];
    }
#pragma unroll
    for (int off = 1; off < 16; off <<= 1)
#pragma unroll
      for (int j = 0; j < 4; ++j) {
        s[j] += __shfl_xor(s[j], off);
        sq[j] += __shfl_xor(sq[j], off);
      }
    if (lr == 0)
#pragma unroll
      for (int j = 0; j < 4; ++j) lnred[rb + j][w] = make_float2(s[j], sq[j]);
    __syncthreads();
#pragma unroll
    for (int j = 0; j < 4; ++j) {
      int row = rb + j;
      float ts = 0.f, tq = 0.f;
#pragma unroll
      for (int k = 0; k < 4; ++k) { float2 p = lnred[row][k]; ts += p.x; tq += p.y; }
      float mu = ts * (1.0f / 128.0f);
      float rstd = rsqrtf(tq * (1.0f / 128.0f) - mu * mu + 1e-6f);
#pragma unroll
      for (int n = 0; n < 2; ++n) {
        int col = cbase + n * 16 + lr;
        Hs[row][col] = f2bf((yreg[n][j] - mu) * rstd * ln2G[col] + ln2B[col]);
      }
    }
  }
  __syncthreads();
  // ---- Phase 3: 4 chunks of W1(relu) -> Mid[c&1] -> barrier -> W2 accumulate ----
  f32x4 acc2[2] = {};
#pragma unroll
  for (int c = 0; c < 4; ++c) {
    bf16x8 w1c[4][2], w2c[4][2];
#pragma unroll
    for (int n = 0; n < 2; ++n) {
      int col = cbase + n * 16 + lr;
#pragma unroll
      for (int kt = 0; kt < 4; ++kt) {
        w1c[kt][n] = *(const bf16x8*)(W1_ + (size_t)(c * 128 + col) * 128 + kt * 32 + lk);
        w2c[kt][n] = *(const bf16x8*)(W2_ + (size_t)col * 512 + c * 128 + kt * 32 + lk);
      }
    }
    f32x4 accm[2] = {};
#pragma unroll
    for (int kt = 0; kt < 4; ++kt) {
      bf16x8 a = *(const bf16x8*)&Hs[lr][kt * 32 + lk];
#pragma unroll
      for (int n = 0; n < 2; ++n)
        accm[n] = __builtin_amdgcn_mfma_f32_16x16x32_bf16(a, w1c[kt][n], accm[n], 0, 0, 0);
    }
#pragma unroll
    for (int n = 0; n < 2; ++n) {
      int col = cbase + n * 16 + lr;
      float b1v = Bl[512 + c * 128 + col];
#pragma unroll
      for (int j = 0; j < 4; ++j)
        Mid[c & 1][rb + j][col] = f2bf(fmaxf(accm[n][j] + b1v, 0.f));
    }
    __syncthreads();
#pragma unroll
    for (int kt = 0; kt < 4; ++kt) {
      bf16x8 a = *(const bf16x8*)&Mid[c & 1][lr][kt * 32 + lk];
#pragma unroll
      for (int n = 0; n < 2; ++n)
        acc2[n] = __builtin_amdgcn_mfma_f32_16x16x32_bf16(a, w2c[kt][n], acc2[n], 0, 0, 0);
    }
    // no trailing barrier: next chunk writes the OTHER Mid buffer
  }
  // ---- Final: b2 + residual(yreg) -> next-LN -> write ----
  {
    float vfin[2][4];
    float s[4] = {}, sq[4] = {};
#pragma unroll
    for (int n = 0; n < 2; ++n) {
      float bval = Bl[1024 + cbase + n * 16 + lr];
#pragma unroll
      for (int j = 0; j < 4; ++j) {
        float v = acc2[n][j] + bval + yreg[n][j];
        vfin[n][j] = v;
        s[j] += v;
        sq[j] = fmaf(v, v, sq[j]);
      }
    }
#pragma unroll
    for (int off = 1; off < 16; off <<= 1)
#pragma unroll
      for (int j = 0; j < 4; ++j) {
        s[j] += __shfl_xor(s[j], off);
        sq[j] += __shfl_xor(sq[j], off);
      }
    if (lr == 0)
#pragma unroll
      for (int j = 0; j < 4; ++j) lnred[rb + j][w] = make_float2(s[j], sq[j]);
    __syncthreads();
#pragma unroll
    for (int j = 0; j < 4; ++j) {
      int row = rb + j;
      float ts = 0.f, tq = 0.f;
#pragma unroll
      for (int k = 0; k < 4; ++k) { float2 p = lnred[row][k]; ts += p.x; tq += p.y; }
      float mu = ts * (1.0f / 128.0f);
      float rstd = rsqrtf(tq * (1.0f / 128.0f) - mu * mu + 1e-6f);
      int grow = r0 + row;
#pragma unroll
      for (int n = 0; n < 2; ++n) {
        int col = cbase + n * 16 + lr;
        float t = (vfin[n][j] - mu) * rstd * lnxG[col] + lnxB[col];
        if (finalMode == 0) {
          Yout[(size_t)grow * 128 + col] = vfin[n][j];
          AbOut[(size_t)grow * 128 + col] = f2bf(t);
        } else {
          Yout[(size_t)grow * 128 + col] = t;
        }
      }
    }
  }
}

// ---- context attention: 32-query chunks, 4 lanes/query, skewed fp32 LDS ----
static constexpr int CTXLD = 134;
__global__ __launch_bounds__(128) void ctx_kernel(
    const unsigned short* __restrict__ qin, const unsigned short* __restrict__ kin,
    unsigned short* __restrict__ cqo, unsigned short* __restrict__ cko) {
  __shared__ float xs[47 * CTXLD];
  const unsigned short* src = blockIdx.y ? kin : qin;
  unsigned short* dst = blockIdx.y ? cko : cqo;
  const size_t rbase = (size_t)blockIdx.x * 256;
  const int t0 = blockIdx.z * 32;
  const int tid = threadIdx.x;
#pragma unroll
  for (int it = 0; it < 6; ++it) {
    int idx = it * 128 + tid;
    int i = idx >> 4, c8 = (idx & 15) * 8;
    if (i < 47) {
      int rg = t0 - 15 + i;
      float f[8];
      if (rg >= 0) {
        ushortx8 wv = *(const ushortx8*)(src + (rbase + rg) * 128 + c8);
#pragma unroll
        for (int j = 0; j < 8; ++j) f[j] = bf2f(wv[j]);
      } else {
#pragma unroll
        for (int j = 0; j < 8; ++j) f[j] = 0.f;
      }
      int base = i * CTXLD + c8 + (c8 >> 5) * 2;
#pragma unroll
      for (int j = 0; j < 8; j += 2)
        *(float2*)&xs[base + j] = make_float2(f[j], f[j + 1]);
    }
  }
  __syncthreads();
  const int ql = tid >> 2, qu = tid & 3;
  const int cb = qu * 34;
  const int cg = qu * 32;
  float ow[32];
#pragma unroll
  for (int c = 0; c < 32; c += 2) {
    float2 w = *(const float2*)&xs[(ql + 15) * CTXLD + cb + c];
    ow[c] = w.x; ow[c + 1] = w.y;
  }
  float p[16];
#pragma unroll
  for (int l = 0; l < 16; ++l) {
    const float* row = &xs[(ql + l) * CTXLD + cb];
    float d = 0.f;
#pragma unroll
    for (int c = 0; c < 32; c += 2) {
      float2 w = *(const float2*)(row + c);
      d = fmaf(ow[c], w.x, d);
      d = fmaf(ow[c + 1], w.y, d);
    }
    p[l] = d;
  }
  float den = 0.f;
#pragma unroll
  for (int l = 0; l < 16; ++l) {
    float sc = p[l] + __shfl_xor(p[l], 1);
    sc += __shfl_xor(sc, 2);
    p[l] = __expf(sc * 0.08838834764831845f);
    den += p[l];
  }
  float o[32];
#pragma unroll
  for (int c = 0; c < 32; ++c) o[c] = 0.f;
#pragma unroll
  for (int l = 0; l < 16; ++l) {
    float pl = p[l];
    const float* row = &xs[(ql + l) * CTXLD + cb];
#pragma unroll
    for (int c = 0; c < 32; c += 2) {
      float2 w = *(const float2*)(row + c);
      o[c] = fmaf(pl, w.x, o[c]);
      o[c + 1] = fmaf(pl, w.y, o[c + 1]);
    }
  }
  float inv = 1.0f / den;
  unsigned short* op = dst + (rbase + t0 + ql) * 128 + cg;
#pragma unroll
  for (int c8 = 0; c8 < 4; ++c8) {
    ushortx8 r;
#pragma unroll
    for (int j = 0; j < 8; ++j) r[j] = f2bf(o[c8 * 8 + j] * inv);
    *(ushortx8*)(op + c8 * 8) = r;
  }
}

// ---- attn1 (MFMA): S^T = CK·CQ^T (32x32x16); P via LDS; O = P·V (16x16x32) ----
static constexpr int PW = 272;
__global__ __launch_bounds__(256) void attn1_kernel(
    const unsigned short* __restrict__ cq, const unsigned short* __restrict__ ck,
    unsigned short* __restrict__ v) {
  __shared__ unsigned short vt[16][PW];
  __shared__ unsigned short ps[4][32][PW];
  __shared__ float rsum[4][32];
  const int bm = blockIdx.x >> 3, h = blockIdx.x & 7;
  const size_t rbase = (size_t)bm * 256;
  const int cbase = h * 16;
  const int tid = threadIdx.x;
  {
    ushortx8 v0 = *(const ushortx8*)(v + (rbase + tid) * 128 + cbase);
    ushortx8 v1 = *(const ushortx8*)(v + (rbase + tid) * 128 + cbase + 8);
#pragma unroll
    for (int d = 0; d < 8; ++d) { vt[d][tid] = v0[d]; vt[8 + d][tid] = v1[d]; }
  }
  __syncthreads();
  const int wid = tid >> 6, lane = tid & 63;
  const int l31 = lane & 31, l15 = lane & 15;
  const int hi5 = lane >> 5, hi4 = lane >> 4;
#pragma unroll
  for (int qt = 0; qt < 2; ++qt) {
    const int q0 = (wid * 2 + qt) * 32;
    bf16x8 bq = *(const bf16x8*)(cq + (rbase + q0 + l31) * 128 + cbase + hi5 * 8);
    float lsum = 0.f;
#pragma unroll
    for (int kt = 0; kt < 8; ++kt) {
      bf16x8 ak = *(const bf16x8*)(ck + (rbase + kt * 32 + l31) * 128 + cbase + hi5 * 8);
      f32x16 z = {};
      f32x16 s = __builtin_amdgcn_mfma_f32_32x32x16_bf16(ak, bq, z, 0, 0, 0);
      float p[16];
#pragma unroll
      for (int r = 0; r < 16; ++r) { p[r] = __expf(s[r] * 0.25f); lsum += p[r]; }
#pragma unroll
      for (int r = 0; r < 16; r += 2) {
        unsigned int pk = cvt_pk_bf16(p[r], p[r + 1]);
        int key = kt * 32 + (r & 3) + 8 * (r >> 2) + 4 * hi5;
        *(unsigned int*)&ps[wid][l31][key] = pk;
      }
    }
    lsum += __shfl_xor(lsum, 32);
    if (lane < 32) rsum[wid][lane] = 1.0f / lsum;
#pragma unroll
    for (int m = 0; m < 2; ++m) {
      f32x4 o = {};
#pragma unroll
      for (int k2 = 0; k2 < 8; ++k2) {
        bf16x8 pa = *(const bf16x8*)&ps[wid][m * 16 + l15][k2 * 32 + hi4 * 8];
        bf16x8 vb = *(const bf16x8*)&vt[l15][k2 * 32 + hi4 * 8];
        o = __builtin_amdgcn_mfma_f32_16x16x32_bf16(pa, vb, o, 0, 0, 0);
      }
      unsigned short* dst = v + (rbase + q0 + m * 16 + hi4 * 4) * 128 + cbase + l15;
#pragma unroll
      for (int j = 0; j < 4; ++j) {
        float inv = rsum[wid][m * 16 + hi4 * 4 + j];
        dst[(size_t)j * 128] = f2bf(o[j] * inv);
      }
    }
  }
}

// ---- attn2 over M=16 axis (bf16 in/out); scrambled write g=q*4+b ----
__global__ __launch_bounds__(128) void attn2_kernel(
    const unsigned short* __restrict__ xa, unsigned short* __restrict__ xr) {
  __shared__ float xas[16][128];
  int b = blockIdx.x >> 8, t = blockIdx.x & 255;
  int tid = threadIdx.x;
#pragma unroll
  for (int jj = 0; jj < 2; ++jj) {
    int idx = tid + (jj << 7);
    int r = idx >> 4, c8 = (idx & 15) * 8;
    ushortx8 vv = *(const ushortx8*)(xa + ((size_t)((b * 16 + r) * 256 + t)) * 128 + c8);
#pragma unroll
    for (int j = 0; j < 8; ++j) xas[r][c8 + j] = bf2f(vv[j]);
  }
  __syncthreads();
  int h = tid >> 4, q = tid & 15;
  float xq[16];
#pragma unroll
  for (int d = 0; d < 16; d++) xq[d] = xas[q][h * 16 + d];
  float sc[16];
  float mx = -1e30f;
#pragma unroll
  for (int k = 0; k < 16; k++) {
    float s = 0.f;
#pragma unroll
    for (int d = 0; d < 16; d++) s += xq[d] * xas[k][h * 16 + d];
    s *= 0.25f;
    sc[k] = s;
    mx = fmaxf(mx, s);
  }
  float den = 0.f;
#pragma unroll
  for (int k = 0; k < 16; k++) { sc[k] = __expf(sc[k] - mx); den += sc[k]; }
  float inv = 1.0f / den;
  float out[16] = {};
#pragma unroll
  for (int k = 0; k < 16; k++) {
    float w = sc[k];
#pragma unroll
    for (int d = 0; d < 16; d++) out[d] += w * xas[k][h * 16 + d];
  }
  int g = q * 4 + b;
  unsigned short* dstp = xr + ((size_t)(g * 256 + t)) * 128 + h * 16;
  ushortx8 r0;
#pragma unroll
  for (int j = 0; j < 8; ++j) r0[j] = f2bf(out[j] * inv);
  *(ushortx8*)dstp = r0;
#pragma unroll
  for (int j = 0; j < 8; ++j) r0[j] = f2bf(out[8 + j] * inv);
  *(ushortx8*)(dstp + 8) = r0;
}

extern "C" void kernel_launch(void* const* d_in, const int* in_sizes, int n_in,
                              void* d_out, int out_size, void* d_ws, size_t ws_size,
                              hipStream_t stream) {
  const float* x    = (const float*)d_in[0];
  const float* Wq   = (const float*)d_in[1];
  const float* bq   = (const float*)d_in[2];
  const float* Wk   = (const float*)d_in[3];
  const float* bk   = (const float*)d_in[4];
  const float* Wv   = (const float*)d_in[5];
  const float* bv   = (const float*)d_in[6];
  const float* Wo   = (const float*)d_in[7];
  const float* bo   = (const float*)d_in[8];
  const float* W1   = (const float*)d_in[9];
  const float* b1   = (const float*)d_in[10];
  const float* W2   = (const float*)d_in[11];
  const float* b2   = (const float*)d_in[12];
  const float* ln1g = (const float*)d_in[13];
  const float* ln1b = (const float*)d_in[14];
  const float* ln2g = (const float*)d_in[15];
  const float* ln2b = (const float*)d_in[16];
  const float* lnfg = (const float*)d_in[17];
  const float* lnfb = (const float*)d_in[18];

  char* base = (char*)d_ws;
  unsigned short* CQb = (unsigned short*)base;                 // [0,4M)
  unsigned short* CKb = (unsigned short*)(base + (4u  << 20)); // [4,8)
  unsigned short* Qb  = (unsigned short*)(base + (8u  << 20)); // [8,12)  Q|K|V contiguous
  unsigned short* Kb  = (unsigned short*)(base + (12u << 20)); // [12,16)
  unsigned short* Vb  = (unsigned short*)(base + (16u << 20)); // [16,20)
  unsigned short* Ab  = (unsigned short*)(base + (20u << 20)); // [20,24)
  unsigned short* Wb  = (unsigned short*)(base + (24u << 20)); // 768 KB
  float*          Bs  = (float*)(base + (24u << 20) + 786432); // 9.2 KB
  float*          Y   = (float*)d_out;

  prep_kernel<<<4297, 256, 0, stream>>>(x, Wq, Wk, Wv, Wo, W1, W2,
                                        bq, bk, bv, bo, b1, b2,
                                        ln1g, ln1b, Wb, Bs, Ab);

  for (int i = 0; i < 2; ++i) {
    const float* rin = i ? Y : x;
    const unsigned short* Wl = Wb + (size_t)i * 196608;
    const float* Bl = Bs + i * 1152;
    gemm_kernel<3, 1><<<1024, 512, 0, stream>>>(Ab, 128, Wl, 128, Bl, Qb, 128);
    ctx_kernel<<<dim3(64, 2, 8), 128, 0, stream>>>(Qb, Kb, CQb, CKb);
    attn1_kernel<<<512, 256, 0, stream>>>(CQb, CKb, Vb);
    attn2_kernel<<<1024, 128, 0, stream>>>(Vb, Ab);
    if (i == 0) {
      ffn_kernel<<<1024, 256, 0, stream>>>(Ab, Wl + 49152, Wl + 65536, Wl + 131072, Bl,
          rin, ln2g, ln2b, ln1g + 128, ln1b + 128, Y, Ab, 0);
    } else {
      ffn_kernel<<<1024, 256, 0, stream>>>(Ab, Wl + 49152, Wl + 65536, Wl + 131072, Bl,
          rin, ln2g + 128, ln2b + 128, lnfg, lnfb, Y, nullptr, 1);
    }
  }
}

// Round 15
// 188.242 us; speedup vs baseline: 1.1550x; 1.1550x over previous
//
#include <hip/hip_runtime.h>
#include <cstddef>
#include <cstdint>

// Shapes: B=4, M=16, T=256, D=128, H=8, CTX=16, L=2
static constexpr int D_ = 128;
static constexpr int NROW = 16384;               // B*M*T rows
static constexpr size_t S_ = (size_t)NROW * D_;  // elems per activation

typedef __attribute__((ext_vector_type(8))) short bf16x8;
typedef __attribute__((ext_vector_type(4))) float f32x4;
typedef __attribute__((ext_vector_type(16))) float f32x16;
typedef __attribute__((ext_vector_type(8))) unsigned short ushortx8;

__device__ __forceinline__ unsigned short f2bf(float f) {
  unsigned int u = __float_as_uint(f);
  u += 0x7fff + ((u >> 16) & 1);
  return (unsigned short)(u >> 16);
}
__device__ __forceinline__ float bf2f(unsigned short h) {
  return __uint_as_float(((unsigned int)h) << 16);
}
__device__ __forceinline__ unsigned int cvt_pk_bf16(float lo, float hi) {
  unsigned int r;
  asm volatile("v_cvt_pk_bf16_f32 %0, %1, %2" : "=v"(r) : "v"(lo), "v"(hi));
  return r;
}
__device__ __forceinline__ float wsum64(float s) {
#pragma unroll
  for (int off = 32; off >= 1; off >>= 1) s += __shfl_xor(s, off);
  return s;
}

// ---- prep: [0,192) wconv | [192,201) bconv | [201,4297) lnconv(x, layer-0) ----
__global__ __launch_bounds__(256) void prep_kernel(
    const float* __restrict__ X,
    const float* __restrict__ Wq, const float* __restrict__ Wk,
    const float* __restrict__ Wv, const float* __restrict__ Wo,
    const float* __restrict__ W1, const float* __restrict__ W2,
    const float* __restrict__ bq, const float* __restrict__ bk,
    const float* __restrict__ bv, const float* __restrict__ bo,
    const float* __restrict__ b1, const float* __restrict__ b2,
    const float* __restrict__ g, const float* __restrict__ b,
    unsigned short* __restrict__ Wb, float* __restrict__ Bs,
    unsigned short* __restrict__ Ab) {
  int bx = blockIdx.x;
  if (bx < 192) {
    size_t i = ((size_t)bx * 256 + threadIdx.x) * 8;
    int layer = i >= 196608;
    size_t o = i - (size_t)layer * 196608;
    const float* src; size_t off;
    if      (o < 16384)  { src = Wq + layer * 16384; off = o; }
    else if (o < 32768)  { src = Wk + layer * 16384; off = o - 16384; }
    else if (o < 49152)  { src = Wv + layer * 16384; off = o - 32768; }
    else if (o < 65536)  { src = Wo + layer * 16384; off = o - 49152; }
    else if (o < 131072) { src = W1 + layer * 65536; off = o - 65536; }
    else                 { src = W2 + layer * 65536; off = o - 131072; }
    ushortx8 r;
#pragma unroll
    for (int j = 0; j < 8; j++) r[j] = f2bf(src[off + j]);
    *(ushortx8*)(Wb + i) = r;
  } else if (bx < 201) {
    int tid = (bx - 192) * 256 + threadIdx.x;
    if (tid >= 2304) return;
    int layer = tid / 1152, o = tid % 1152;
    float v;
    if      (o < 128)  v = bq[layer * 128 + o];
    else if (o < 256)  v = bk[layer * 128 + o - 128];
    else if (o < 384)  v = bv[layer * 128 + o - 256];
    else if (o < 512)  v = bo[layer * 128 + o - 384];
    else if (o < 1024) v = b1[layer * 512 + o - 512];
    else               v = b2[layer * 128 + o - 1024];
    Bs[tid] = v;
  } else {
    int wid = threadIdx.x >> 6, lane = threadIdx.x & 63;
    int row = ((bx - 201) << 2) + wid;
    float2 xv = *(const float2*)(X + (size_t)row * D_ + lane * 2);
    float s = wsum64(xv.x + xv.y);
    float sq = wsum64(xv.x * xv.x + xv.y * xv.y);
    float mu = s * (1.0f / 128.0f);
    float var = sq * (1.0f / 128.0f) - mu * mu;
    float rstd = rsqrtf(var + 1e-6f);
    float2 gv = *(const float2*)(g + lane * 2);
    float2 bv2 = *(const float2*)(b + lane * 2);
    unsigned int lo = f2bf((xv.x - mu) * rstd * gv.x + bv2.x);
    unsigned int hi = f2bf((xv.y - mu) * rstd * gv.y + bv2.y);
    *(unsigned int*)(Ab + (size_t)row * D_ + lane * 2) = lo | (hi << 16);
  }
}

// ---- bf16 MFMA GEMM (QKV): 16-row blocks, 8 col-waves ----
template <int NT, int ROWW>
__global__ __launch_bounds__(512, 2) void gemm_kernel(
    const unsigned short* __restrict__ A, int lda,
    const unsigned short* __restrict__ W, int ldw,
    const float* __restrict__ bias,
    unsigned short* __restrict__ Cb, int K) {
  constexpr int COLW = 8 / ROWW;
  const int w = threadIdx.x >> 6;
  const int l = threadIdx.x & 63;
  const int rw = w / COLW, cw = w % COLW;
  const int r0 = blockIdx.x * (16 * ROWW) + rw * 16;
  const int c0 = cw * (NT * 16);
  const int lr = l & 15, lk = (l >> 4) * 8;
  f32x4 acc[NT] = {};
  const unsigned short* Ap = A + (size_t)(r0 + lr) * lda + lk;
  const unsigned short* Wp = W + (size_t)(c0 + lr) * ldw + lk;
  for (int kb = 0; kb < K; kb += 128) {
    bf16x8 aF[4];
    bf16x8 wF[4][NT];
#pragma unroll
    for (int kt = 0; kt < 4; ++kt) {
      int k0 = kb + kt * 32;
      aF[kt] = *(const bf16x8*)(Ap + k0);
#pragma unroll
      for (int n = 0; n < NT; ++n)
        wF[kt][n] = *(const bf16x8*)(Wp + (size_t)(n * 16) * ldw + k0);
    }
#pragma unroll
    for (int kt = 0; kt < 4; ++kt)
#pragma unroll
      for (int n = 0; n < NT; ++n)
        acc[n] = __builtin_amdgcn_mfma_f32_16x16x32_bf16(aF[kt], wF[kt][n], acc[n], 0, 0, 0);
  }
  const int rb = (l >> 4) * 4;
#pragma unroll
  for (int n = 0; n < NT; ++n) {
    int col = c0 + n * 16 + lr;
    float bval = bias[col];
    unsigned short* dst = Cb + (size_t)(col >> 7) * S_ + (col & 127);
#pragma unroll
    for (int j = 0; j < 4; ++j)
      dst[(size_t)(r0 + rb + j) * 128] = f2bf(acc[n][j] + bval);
  }
}

// ---- fused half-layer v2 (best): 64-row blocks, grid 256, 8 waves col-split.
//      NOTE: Abuf and AbOut must NOT alias (restrict) — launcher guarantees it. ----
static constexpr int LDH = 136;
__global__ __launch_bounds__(512, 2) void ffn_kernel(
    const unsigned short* __restrict__ Abuf,
    const unsigned short* __restrict__ Wo_, const unsigned short* __restrict__ W1_,
    const unsigned short* __restrict__ W2_, const float* __restrict__ Bl,
    const float* __restrict__ rin,
    const float* __restrict__ ln2G, const float* __restrict__ ln2B,
    const float* __restrict__ lnxG, const float* __restrict__ lnxB,
    float* __restrict__ Yout, unsigned short* __restrict__ AbOut, int finalMode) {
  __shared__ unsigned short As[64][LDH];
  __shared__ unsigned short Hs[64][LDH];
  __shared__ unsigned short Mid[64][LDH];
  __shared__ float2 lnred[64][8];
  const int tid = threadIdx.x;
  const int w = tid >> 6, l = tid & 63;
  const int r0 = blockIdx.x * 64;
  const int lr = l & 15, lk = (l >> 4) * 8, rb = (l >> 4) * 4;
  const int col = w * 16 + lr;

  bf16x8 wof[4], w1f[4], w2f[4];
#pragma unroll
  for (int kt = 0; kt < 4; ++kt) {
    wof[kt] = *(const bf16x8*)(Wo_ + (size_t)col * 128 + kt * 32 + lk);
    w1f[kt] = *(const bf16x8*)(W1_ + (size_t)col * 128 + kt * 32 + lk);
    w2f[kt] = *(const bf16x8*)(W2_ + (size_t)col * 512 + kt * 32 + lk);
  }
#pragma unroll
  for (int itr = 0; itr < 2; ++itr) {
    int idx = itr * 512 + tid;
    int r = idx >> 4, c8 = (idx & 15) * 8;
    *(ushortx8*)&As[r][c8] = *(const ushortx8*)(Abuf + (size_t)(r0 + r) * 128 + c8);
  }
  __syncthreads();

  f32x4 acc1[4] = {};
#pragma unroll
  for (int kt = 0; kt < 4; ++kt)
#pragma unroll
    for (int m = 0; m < 4; ++m) {
      bf16x8 a = *(const bf16x8*)&As[m * 16 + lr][kt * 32 + lk];
      acc1[m] = __builtin_amdgcn_mfma_f32_16x16x32_bf16(a, wof[kt], acc1[m], 0, 0, 0);
    }
  float yreg[4][4];
  {
    float bval = Bl[384 + col];
#pragma unroll
    for (int m = 0; m < 4; ++m)
#pragma unroll
      for (int j = 0; j < 4; ++j)
        yreg[m][j] = acc1[m][j] + bval + rin[(size_t)(r0 + m * 16 + rb + j) * 128 + col];
  }
  {
    float s[4][4], sq[4][4];
#pragma unroll
    for (int m = 0; m < 4; ++m)
#pragma unroll
      for (int j = 0; j < 4; ++j) { s[m][j] = yreg[m][j]; sq[m][j] = yreg[m][j] * yreg[m][j]; }
#pragma unroll
    for (int off = 1; off < 16; off <<= 1)
#pragma unroll
      for (int m = 0; m < 4; ++m)
#pragma unroll
        for (int j = 0; j < 4; ++j) {
          s[m][j] += __shfl_xor(s[m][j], off);
          sq[m][j] += __shfl_xor(sq[m][j], off);
        }
    if (lr == 0)
#pragma unroll
      for (int m = 0; m < 4; ++m)
#pragma unroll
        for (int j = 0; j < 4; ++j)
          lnred[m * 16 + rb + j][w] = make_float2(s[m][j], sq[m][j]);
    __syncthreads();
    if (tid < 64) {
      float ts = 0.f, tq = 0.f;
#pragma unroll
      for (int k = 0; k < 8; ++k) { float2 p = lnred[tid][k]; ts += p.x; tq += p.y; }
      float mu = ts * (1.0f / 128.0f);
      float rstd = rsqrtf(tq * (1.0f / 128.0f) - mu * mu + 1e-6f);
      lnred[tid][0] = make_float2(mu, rstd);
    }
    __syncthreads();
    float g = ln2G[col], bb = ln2B[col];
#pragma unroll
    for (int m = 0; m < 4; ++m)
#pragma unroll
      for (int j = 0; j < 4; ++j) {
        float2 st = lnred[m * 16 + rb + j][0];
        Hs[m * 16 + rb + j][col] = f2bf((yreg[m][j] - st.x) * st.y * g + bb);
      }
  }
  __syncthreads();
  f32x4 acc2[4] = {};
#pragma unroll
  for (int c = 0; c < 4; ++c) {
    bf16x8 w1n[4], w2n[4];
    if (c < 3) {
#pragma unroll
      for (int kt = 0; kt < 4; ++kt) {
        w1n[kt] = *(const bf16x8*)(W1_ + (size_t)((c + 1) * 128 + col) * 128 + kt * 32 + lk);
        w2n[kt] = *(const bf16x8*)(W2_ + (size_t)col * 512 + (c + 1) * 128 + kt * 32 + lk);
      }
    }
    f32x4 accm[4] = {};
#pragma unroll
    for (int kt = 0; kt < 4; ++kt)
#pragma unroll
      for (int m = 0; m < 4; ++m) {
        bf16x8 a = *(const bf16x8*)&Hs[m * 16 + lr][kt * 32 + lk];
        accm[m] = __builtin_amdgcn_mfma_f32_16x16x32_bf16(a, w1f[kt], accm[m], 0, 0, 0);
      }
    float b1v = Bl[512 + c * 128 + col];
#pragma unroll
    for (int m = 0; m < 4; ++m)
#pragma unroll
      for (int j = 0; j < 4; ++j)
        Mid[m * 16 + rb + j][col] = f2bf(fmaxf(accm[m][j] + b1v, 0.f));
    __syncthreads();
#pragma unroll
    for (int kt = 0; kt < 4; ++kt)
#pragma unroll
      for (int m = 0; m < 4; ++m) {
        bf16x8 a = *(const bf16x8*)&Mid[m * 16 + lr][kt * 32 + lk];
        acc2[m] = __builtin_amdgcn_mfma_f32_16x16x32_bf16(a, w2f[kt], acc2[m], 0, 0, 0);
      }
    __syncthreads();
    if (c < 3) {
#pragma unroll
      for (int kt = 0; kt < 4; ++kt) { w1f[kt] = w1n[kt]; w2f[kt] = w2n[kt]; }
    }
  }
  float vfin[4][4];
  {
    float bval = Bl[1024 + col];
    float s[4][4], sq[4][4];
#pragma unroll
    for (int m = 0; m < 4; ++m)
#pragma unroll
      for (int j = 0; j < 4; ++j) {
        float v = acc2[m][j] + bval + yreg[m][j];
        vfin[m][j] = v;
        s[m][j] = v;
        sq[m][j] = v * v;
      }
#pragma unroll
    for (int off = 1; off < 16; off <<= 1)
#pragma unroll
      for (int m = 0; m < 4; ++m)
#pragma unroll
        for (int j = 0; j < 4; ++j) {
          s[m][j] += __shfl_xor(s[m][j], off);
          sq[m][j] += __shfl_xor(sq[m][j], off);
        }
    if (lr == 0)
#pragma unroll
      for (int m = 0; m < 4; ++m)
#pragma unroll
        for (int j = 0; j < 4; ++j)
          lnred[m * 16 + rb + j][w] = make_float2(s[m][j], sq[m][j]);
    __syncthreads();
    if (tid < 64) {
      float ts = 0.f, tq = 0.f;
#pragma unroll
      for (int k = 0; k < 8; ++k) { float2 p = lnred[tid][k]; ts += p.x; tq += p.y; }
      float mu = ts * (1.0f / 128.0f);
      float rstd = rsqrtf(tq * (1.0f / 128.0f) - mu * mu + 1e-6f);
      lnred[tid][0] = make_float2(mu, rstd);
    }
    __syncthreads();
    float g = lnxG[col], bb = lnxB[col];
#pragma unroll
    for (int m = 0; m < 4; ++m)
#pragma unroll
      for (int j = 0; j < 4; ++j) {
        int row = r0 + m * 16 + rb + j;
        float2 st = lnred[m * 16 + rb + j][0];
        float t = (vfin[m][j] - st.x) * st.y * g + bb;
        if (finalMode == 0) {
          Yout[(size_t)row * 128 + col] = vfin[m][j];
          AbOut[(size_t)row * 128 + col] = f2bf(t);
        } else {
          Yout[(size_t)row * 128 + col] = t;
        }
      }
  }
}

// ---- context attention: 32-query chunks, 4 lanes/query, skewed fp32 LDS ----
static constexpr int CTXLD = 134;
__global__ __launch_bounds__(128) void ctx_kernel(
    const unsigned short* __restrict__ qin, const unsigned short* __restrict__ kin,
    unsigned short* __restrict__ cqo, unsigned short* __restrict__ cko) {
  __shared__ float xs[47 * CTXLD];
  const unsigned short* src = blockIdx.y ? kin : qin;
  unsigned short* dst = blockIdx.y ? cko : cqo;
  const size_t rbase = (size_t)blockIdx.x * 256;
  const int t0 = blockIdx.z * 32;
  const int tid = threadIdx.x;
#pragma unroll
  for (int it = 0; it < 6; ++it) {
    int idx = it * 128 + tid;
    int i = idx >> 4, c8 = (idx & 15) * 8;
    if (i < 47) {
      int rg = t0 - 15 + i;
      float f[8];
      if (rg >= 0) {
        ushortx8 wv = *(const ushortx8*)(src + (rbase + rg) * 128 + c8);
#pragma unroll
        for (int j = 0; j < 8; ++j) f[j] = bf2f(wv[j]);
      } else {
#pragma unroll
        for (int j = 0; j < 8; ++j) f[j] = 0.f;
      }
      int base = i * CTXLD + c8 + (c8 >> 5) * 2;
#pragma unroll
      for (int j = 0; j < 8; j += 2)
        *(float2*)&xs[base + j] = make_float2(f[j], f[j + 1]);
    }
  }
  __syncthreads();
  const int ql = tid >> 2, qu = tid & 3;
  const int cb = qu * 34;
  const int cg = qu * 32;
  float ow[32];
#pragma unroll
  for (int c = 0; c < 32; c += 2) {
    float2 w = *(const float2*)&xs[(ql + 15) * CTXLD + cb + c];
    ow[c] = w.x; ow[c + 1] = w.y;
  }
  float p[16];
#pragma unroll
  for (int l = 0; l < 16; ++l) {
    const float* row = &xs[(ql + l) * CTXLD + cb];
    float d = 0.f;
#pragma unroll
    for (int c = 0; c < 32; c += 2) {
      float2 w = *(const float2*)(row + c);
      d = fmaf(ow[c], w.x, d);
      d = fmaf(ow[c + 1], w.y, d);
    }
    p[l] = d;
  }
  float den = 0.f;
#pragma unroll
  for (int l = 0; l < 16; ++l) {
    float sc = p[l] + __shfl_xor(p[l], 1);
    sc += __shfl_xor(sc, 2);
    p[l] = __expf(sc * 0.08838834764831845f);
    den += p[l];
  }
  float o[32];
#pragma unroll
  for (int c = 0; c < 32; ++c) o[c] = 0.f;
#pragma unroll
  for (int l = 0; l < 16; ++l) {
    float pl = p[l];
    const float* row = &xs[(ql + l) * CTXLD + cb];
#pragma unroll
    for (int c = 0; c < 32; c += 2) {
      float2 w = *(const float2*)(row + c);
      o[c] = fmaf(pl, w.x, o[c]);
      o[c + 1] = fmaf(pl, w.y, o[c + 1]);
    }
  }
  float inv = 1.0f / den;
  unsigned short* op = dst + (rbase + t0 + ql) * 128 + cg;
#pragma unroll
  for (int c8 = 0; c8 < 4; ++c8) {
    ushortx8 r;
#pragma unroll
    for (int j = 0; j < 8; ++j) r[j] = f2bf(o[c8 * 8 + j] * inv);
    *(ushortx8*)(op + c8 * 8) = r;
  }
}

// ---- attn1 (MFMA): S^T = CK·CQ^T (32x32x16); P via LDS; O = P·V (16x16x32) ----
static constexpr int PW = 272;
__global__ __launch_bounds__(256) void attn1_kernel(
    const unsigned short* __restrict__ cq, const unsigned short* __restrict__ ck,
    unsigned short* v) {
  __shared__ unsigned short vt[16][PW];
  __shared__ unsigned short ps[4][32][PW];
  __shared__ float rsum[4][32];
  const int bm = blockIdx.x >> 3, h = blockIdx.x & 7;
  const size_t rbase = (size_t)bm * 256;
  const int cbase = h * 16;
  const int tid = threadIdx.x;
  {
    ushortx8 v0 = *(const ushortx8*)(v + (rbase + tid) * 128 + cbase);
    ushortx8 v1 = *(const ushortx8*)(v + (rbase + tid) * 128 + cbase + 8);
#pragma unroll
    for (int d = 0; d < 8; ++d) { vt[d][tid] = v0[d]; vt[8 + d][tid] = v1[d]; }
  }
  __syncthreads();
  const int wid = tid >> 6, lane = tid & 63;
  const int l31 = lane & 31, l15 = lane & 15;
  const int hi5 = lane >> 5, hi4 = lane >> 4;
#pragma unroll
  for (int qt = 0; qt < 2; ++qt) {
    const int q0 = (wid * 2 + qt) * 32;
    bf16x8 bq = *(const bf16x8*)(cq + (rbase + q0 + l31) * 128 + cbase + hi5 * 8);
    float lsum = 0.f;
#pragma unroll
    for (int kt = 0; kt < 8; ++kt) {
      bf16x8 ak = *(const bf16x8*)(ck + (rbase + kt * 32 + l31) * 128 + cbase + hi5 * 8);
      f32x16 z = {};
      f32x16 s = __builtin_amdgcn_mfma_f32_32x32x16_bf16(ak, bq, z, 0, 0, 0);
      float p[16];
#pragma unroll
      for (int r = 0; r < 16; ++r) { p[r] = __expf(s[r] * 0.25f); lsum += p[r]; }
#pragma unroll
      for (int r = 0; r < 16; r += 2) {
        unsigned int pk = cvt_pk_bf16(p[r], p[r + 1]);
        int key = kt * 32 + (r & 3) + 8 * (r >> 2) + 4 * hi5;
        *(unsigned int*)&ps[wid][l31][key] = pk;
      }
    }
    lsum += __shfl_xor(lsum, 32);
    if (lane < 32) rsum[wid][lane] = 1.0f / lsum;
#pragma unroll
    for (int m = 0; m < 2; ++m) {
      f32x4 o = {};
#pragma unroll
      for (int k2 = 0; k2 < 8; ++k2) {
        bf16x8 pa = *(const bf16x8*)&ps[wid][m * 16 + l15][k2 * 32 + hi4 * 8];
        bf16x8 vb = *(const bf16x8*)&vt[l15][k2 * 32 + hi4 * 8];
        o = __builtin_amdgcn_mfma_f32_16x16x32_bf16(pa, vb, o, 0, 0, 0);
      }
      unsigned short* dst = v + (rbase + q0 + m * 16 + hi4 * 4) * 128 + cbase + l15;
#pragma unroll
      for (int j = 0; j < 4; ++j) {
        float inv = rsum[wid][m * 16 + hi4 * 4 + j];
        dst[(size_t)j * 128] = f2bf(o[j] * inv);
      }
    }
  }
}

// ---- attn2 over M=16 axis (bf16 in/out); scrambled write g=q*4+b ----
__global__ __launch_bounds__(128) void attn2_kernel(
    const unsigned short* __restrict__ xa, unsigned short* __restrict__ xr) {
  __shared__ float xas[16][128];
  int b = blockIdx.x >> 8, t = blockIdx.x & 255;
  int tid = threadIdx.x;
#pragma unroll
  for (int jj = 0; jj < 2; ++jj) {
    int idx = tid + (jj << 7);
    int r = idx >> 4, c8 = (idx & 15) * 8;
    ushortx8 vv = *(const ushortx8*)(xa + ((size_t)((b * 16 + r) * 256 + t)) * 128 + c8);
#pragma unroll
    for (int j = 0; j < 8; ++j) xas[r][c8 + j] = bf2f(vv[j]);
  }
  __syncthreads();
  int h = tid >> 4, q = tid & 15;
  float xq[16];
#pragma unroll
  for (int d = 0; d < 16; d++) xq[d] = xas[q][h * 16 + d];
  float sc[16];
  float mx = -1e30f;
#pragma unroll
  for (int k = 0; k < 16; k++) {
    float s = 0.f;
#pragma unroll
    for (int d = 0; d < 16; d++) s += xq[d] * xas[k][h * 16 + d];
    s *= 0.25f;
    sc[k] = s;
    mx = fmaxf(mx, s);
  }
  float den = 0.f;
#pragma unroll
  for (int k = 0; k < 16; k++) { sc[k] = __expf(sc[k] - mx); den += sc[k]; }
  float inv = 1.0f / den;
  float out[16] = {};
#pragma unroll
  for (int k = 0; k < 16; k++) {
    float w = sc[k];
#pragma unroll
    for (int d = 0; d < 16; d++) out[d] += w * xas[k][h * 16 + d];
  }
  int g = q * 4 + b;
  unsigned short* dstp = xr + ((size_t)(g * 256 + t)) * 128 + h * 16;
  ushortx8 r0;
#pragma unroll
  for (int j = 0; j < 8; ++j) r0[j] = f2bf(out[j] * inv);
  *(ushortx8*)dstp = r0;
#pragma unroll
  for (int j = 0; j < 8; ++j) r0[j] = f2bf(out[8 + j] * inv);
  *(ushortx8*)(dstp + 8) = r0;
}

extern "C" void kernel_launch(void* const* d_in, const int* in_sizes, int n_in,
                              void* d_out, int out_size, void* d_ws, size_t ws_size,
                              hipStream_t stream) {
  const float* x    = (const float*)d_in[0];
  const float* Wq   = (const float*)d_in[1];
  const float* bq   = (const float*)d_in[2];
  const float* Wk   = (const float*)d_in[3];
  const float* bk   = (const float*)d_in[4];
  const float* Wv   = (const float*)d_in[5];
  const float* bv   = (const float*)d_in[6];
  const float* Wo   = (const float*)d_in[7];
  const float* bo   = (const float*)d_in[8];
  const float* W1   = (const float*)d_in[9];
  const float* b1   = (const float*)d_in[10];
  const float* W2   = (const float*)d_in[11];
  const float* b2   = (const float*)d_in[12];
  const float* ln1g = (const float*)d_in[13];
  const float* ln1b = (const float*)d_in[14];
  const float* ln2g = (const float*)d_in[15];
  const float* ln2b = (const float*)d_in[16];
  const float* lnfg = (const float*)d_in[17];
  const float* lnfb = (const float*)d_in[18];

  char* base = (char*)d_ws;
  unsigned short* CQb = (unsigned short*)base;                 // [0,4M)  ctx-out / layer-1 LN1 act
  unsigned short* CKb = (unsigned short*)(base + (4u  << 20)); // [4,8)
  unsigned short* Qb  = (unsigned short*)(base + (8u  << 20)); // [8,12)  Q|K|V contiguous
  unsigned short* Kb  = (unsigned short*)(base + (12u << 20)); // [12,16)
  unsigned short* Vb  = (unsigned short*)(base + (16u << 20)); // [16,20)
  unsigned short* Ab  = (unsigned short*)(base + (20u << 20)); // [20,24)
  unsigned short* Wb  = (unsigned short*)(base + (24u << 20)); // 768 KB
  float*          Bs  = (float*)(base + (24u << 20) + 786432); // 9.2 KB
  float*          Y   = (float*)d_out;

  prep_kernel<<<4297, 256, 0, stream>>>(x, Wq, Wk, Wv, Wo, W1, W2,
                                        bq, bk, bv, bo, b1, b2,
                                        ln1g, ln1b, Wb, Bs, Ab);

  for (int i = 0; i < 2; ++i) {
    const float* rin = i ? Y : x;
    const unsigned short* Wl = Wb + (size_t)i * 196608;
    const float* Bl = Bs + i * 1152;
    // layer-0 LN1 act lives in Ab; layer-1 LN1 act was written to CQb by ffn (no aliasing)
    const unsigned short* Acur = (i == 0) ? Ab : CQb;
    gemm_kernel<3, 1><<<1024, 512, 0, stream>>>(Acur, 128, Wl, 128, Bl, Qb, 128);
    ctx_kernel<<<dim3(64, 2, 8), 128, 0, stream>>>(Qb, Kb, CQb, CKb);
    attn1_kernel<<<512, 256, 0, stream>>>(CQb, CKb, Vb);
    attn2_kernel<<<1024, 128, 0, stream>>>(Vb, Ab);
    if (i == 0) {
      // writes Y (raw fp32) and CQb = LN1_layer1(Y) bf16  [distinct from Abuf=Ab]
      ffn_kernel<<<256, 512, 0, stream>>>(Ab, Wl + 49152, Wl + 65536, Wl + 131072, Bl,
          rin, ln2g, ln2b, ln1g + 128, ln1b + 128, Y, CQb, 0);
    } else {
      ffn_kernel<<<256, 512, 0, stream>>>(Ab, Wl + 49152, Wl + 65536, Wl + 131072, Bl,
          rin, ln2g + 128, ln2b + 128, lnfg, lnfb, Y, nullptr, 1);
    }
  }
}

// Round 16
// 173.825 us; speedup vs baseline: 1.2508x; 1.0829x over previous
//
#include <hip/hip_runtime.h>
#include <cstddef>
#include <cstdint>

// Shapes: B=4, M=16, T=256, D=128, H=8, CTX=16, L=2
static constexpr int D_ = 128;
static constexpr int NROW = 16384;               // B*M*T rows
static constexpr size_t S_ = (size_t)NROW * D_;  // elems per activation

typedef __attribute__((ext_vector_type(8))) short bf16x8;
typedef __attribute__((ext_vector_type(4))) float f32x4;
typedef __attribute__((ext_vector_type(16))) float f32x16;
typedef __attribute__((ext_vector_type(8))) unsigned short ushortx8;

__device__ __forceinline__ unsigned short f2bf(float f) {
  unsigned int u = __float_as_uint(f);
  u += 0x7fff + ((u >> 16) & 1);
  return (unsigned short)(u >> 16);
}
__device__ __forceinline__ float bf2f(unsigned short h) {
  return __uint_as_float(((unsigned int)h) << 16);
}
__device__ __forceinline__ unsigned int cvt_pk_bf16(float lo, float hi) {
  unsigned int r;
  asm volatile("v_cvt_pk_bf16_f32 %0, %1, %2" : "=v"(r) : "v"(lo), "v"(hi));
  return r;
}
__device__ __forceinline__ float wsum64(float s) {
#pragma unroll
  for (int off = 32; off >= 1; off >>= 1) s += __shfl_xor(s, off);
  return s;
}

// ---- prep: [0,192) wconv | [192,201) bconv | [201,4297) lnconv(x, layer-0) ----
__global__ __launch_bounds__(256) void prep_kernel(
    const float* __restrict__ X,
    const float* __restrict__ Wq, const float* __restrict__ Wk,
    const float* __restrict__ Wv, const float* __restrict__ Wo,
    const float* __restrict__ W1, const float* __restrict__ W2,
    const float* __restrict__ bq, const float* __restrict__ bk,
    const float* __restrict__ bv, const float* __restrict__ bo,
    const float* __restrict__ b1, const float* __restrict__ b2,
    const float* __restrict__ g, const float* __restrict__ b,
    unsigned short* __restrict__ Wb, float* __restrict__ Bs,
    unsigned short* __restrict__ Ab) {
  int bx = blockIdx.x;
  if (bx < 192) {
    size_t i = ((size_t)bx * 256 + threadIdx.x) * 8;
    int layer = i >= 196608;
    size_t o = i - (size_t)layer * 196608;
    const float* src; size_t off;
    if      (o < 16384)  { src = Wq + layer * 16384; off = o; }
    else if (o < 32768)  { src = Wk + layer * 16384; off = o - 16384; }
    else if (o < 49152)  { src = Wv + layer * 16384; off = o - 32768; }
    else if (o < 65536)  { src = Wo + layer * 16384; off = o - 49152; }
    else if (o < 131072) { src = W1 + layer * 65536; off = o - 65536; }
    else                 { src = W2 + layer * 65536; off = o - 131072; }
    ushortx8 r;
#pragma unroll
    for (int j = 0; j < 8; j++) r[j] = f2bf(src[off + j]);
    *(ushortx8*)(Wb + i) = r;
  } else if (bx < 201) {
    int tid = (bx - 192) * 256 + threadIdx.x;
    if (tid >= 2304) return;
    int layer = tid / 1152, o = tid % 1152;
    float v;
    if      (o < 128)  v = bq[layer * 128 + o];
    else if (o < 256)  v = bk[layer * 128 + o - 128];
    else if (o < 384)  v = bv[layer * 128 + o - 256];
    else if (o < 512)  v = bo[layer * 128 + o - 384];
    else if (o < 1024) v = b1[layer * 512 + o - 512];
    else               v = b2[layer * 128 + o - 1024];
    Bs[tid] = v;
  } else {
    int wid = threadIdx.x >> 6, lane = threadIdx.x & 63;
    int row = ((bx - 201) << 2) + wid;
    float2 xv = *(const float2*)(X + (size_t)row * D_ + lane * 2);
    float s = wsum64(xv.x + xv.y);
    float sq = wsum64(xv.x * xv.x + xv.y * xv.y);
    float mu = s * (1.0f / 128.0f);
    float var = sq * (1.0f / 128.0f) - mu * mu;
    float rstd = rsqrtf(var + 1e-6f);
    float2 gv = *(const float2*)(g + lane * 2);
    float2 bv2 = *(const float2*)(b + lane * 2);
    unsigned int lo = f2bf((xv.x - mu) * rstd * gv.x + bv2.x);
    unsigned int hi = f2bf((xv.y - mu) * rstd * gv.y + bv2.y);
    *(unsigned int*)(Ab + (size_t)row * D_ + lane * 2) = lo | (hi << 16);
  }
}

// ---- bf16 MFMA GEMM (QKV): 16-row blocks, 8 col-waves ----
template <int NT, int ROWW>
__global__ __launch_bounds__(512, 2) void gemm_kernel(
    const unsigned short* __restrict__ A, int lda,
    const unsigned short* __restrict__ W, int ldw,
    const float* __restrict__ bias,
    unsigned short* __restrict__ Cb, int K) {
  constexpr int COLW = 8 / ROWW;
  const int w = threadIdx.x >> 6;
  const int l = threadIdx.x & 63;
  const int rw = w / COLW, cw = w % COLW;
  const int r0 = blockIdx.x * (16 * ROWW) + rw * 16;
  const int c0 = cw * (NT * 16);
  const int lr = l & 15, lk = (l >> 4) * 8;
  f32x4 acc[NT] = {};
  const unsigned short* Ap = A + (size_t)(r0 + lr) * lda + lk;
  const unsigned short* Wp = W + (size_t)(c0 + lr) * ldw + lk;
  for (int kb = 0; kb < K; kb += 128) {
    bf16x8 aF[4];
    bf16x8 wF[4][NT];
#pragma unroll
    for (int kt = 0; kt < 4; ++kt) {
      int k0 = kb + kt * 32;
      aF[kt] = *(const bf16x8*)(Ap + k0);
#pragma unroll
      for (int n = 0; n < NT; ++n)
        wF[kt][n] = *(const bf16x8*)(Wp + (size_t)(n * 16) * ldw + k0);
    }
#pragma unroll
    for (int kt = 0; kt < 4; ++kt)
#pragma unroll
      for (int n = 0; n < NT; ++n)
        acc[n] = __builtin_amdgcn_mfma_f32_16x16x32_bf16(aF[kt], wF[kt][n], acc[n], 0, 0, 0);
  }
  const int rb = (l >> 4) * 4;
#pragma unroll
  for (int n = 0; n < NT; ++n) {
    int col = c0 + n * 16 + lr;
    float bval = bias[col];
    unsigned short* dst = Cb + (size_t)(col >> 7) * S_ + (col & 127);
#pragma unroll
    for (int j = 0; j < 4; ++j)
      dst[(size_t)(r0 + rb + j) * 128] = f2bf(acc[n][j] + bval);
  }
}

// ---- fused half-layer v2 (best): 64-row blocks, grid 256, 8 waves col-split.
//      NOTE: Abuf and AbOut must NOT alias — launcher guarantees it. ----
static constexpr int LDH = 136;
__global__ __launch_bounds__(512, 2) void ffn_kernel(
    const unsigned short* __restrict__ Abuf,
    const unsigned short* __restrict__ Wo_, const unsigned short* __restrict__ W1_,
    const unsigned short* __restrict__ W2_, const float* __restrict__ Bl,
    const float* __restrict__ rin,
    const float* __restrict__ ln2G, const float* __restrict__ ln2B,
    const float* __restrict__ lnxG, const float* __restrict__ lnxB,
    float* __restrict__ Yout, unsigned short* __restrict__ AbOut, int finalMode) {
  __shared__ unsigned short As[64][LDH];
  __shared__ unsigned short Hs[64][LDH];
  __shared__ unsigned short Mid[64][LDH];
  __shared__ float2 lnred[64][8];
  const int tid = threadIdx.x;
  const int w = tid >> 6, l = tid & 63;
  const int r0 = blockIdx.x * 64;
  const int lr = l & 15, lk = (l >> 4) * 8, rb = (l >> 4) * 4;
  const int col = w * 16 + lr;

  bf16x8 wof[4], w1f[4], w2f[4];
#pragma unroll
  for (int kt = 0; kt < 4; ++kt) {
    wof[kt] = *(const bf16x8*)(Wo_ + (size_t)col * 128 + kt * 32 + lk);
    w1f[kt] = *(const bf16x8*)(W1_ + (size_t)col * 128 + kt * 32 + lk);
    w2f[kt] = *(const bf16x8*)(W2_ + (size_t)col * 512 + kt * 32 + lk);
  }
#pragma unroll
  for (int itr = 0; itr < 2; ++itr) {
    int idx = itr * 512 + tid;
    int r = idx >> 4, c8 = (idx & 15) * 8;
    *(ushortx8*)&As[r][c8] = *(const ushortx8*)(Abuf + (size_t)(r0 + r) * 128 + c8);
  }
  __syncthreads();

  f32x4 acc1[4] = {};
#pragma unroll
  for (int kt = 0; kt < 4; ++kt)
#pragma unroll
    for (int m = 0; m < 4; ++m) {
      bf16x8 a = *(const bf16x8*)&As[m * 16 + lr][kt * 32 + lk];
      acc1[m] = __builtin_amdgcn_mfma_f32_16x16x32_bf16(a, wof[kt], acc1[m], 0, 0, 0);
    }
  float yreg[4][4];
  {
    float bval = Bl[384 + col];
#pragma unroll
    for (int m = 0; m < 4; ++m)
#pragma unroll
      for (int j = 0; j < 4; ++j)
        yreg[m][j] = acc1[m][j] + bval + rin[(size_t)(r0 + m * 16 + rb + j) * 128 + col];
  }
  {
    float s[4][4], sq[4][4];
#pragma unroll
    for (int m = 0; m < 4; ++m)
#pragma unroll
      for (int j = 0; j < 4; ++j) { s[m][j] = yreg[m][j]; sq[m][j] = yreg[m][j] * yreg[m][j]; }
#pragma unroll
    for (int off = 1; off < 16; off <<= 1)
#pragma unroll
      for (int m = 0; m < 4; ++m)
#pragma unroll
        for (int j = 0; j < 4; ++j) {
          s[m][j] += __shfl_xor(s[m][j], off);
          sq[m][j] += __shfl_xor(sq[m][j], off);
        }
    if (lr == 0)
#pragma unroll
      for (int m = 0; m < 4; ++m)
#pragma unroll
        for (int j = 0; j < 4; ++j)
          lnred[m * 16 + rb + j][w] = make_float2(s[m][j], sq[m][j]);
    __syncthreads();
    if (tid < 64) {
      float ts = 0.f, tq = 0.f;
#pragma unroll
      for (int k = 0; k < 8; ++k) { float2 p = lnred[tid][k]; ts += p.x; tq += p.y; }
      float mu = ts * (1.0f / 128.0f);
      float rstd = rsqrtf(tq * (1.0f / 128.0f) - mu * mu + 1e-6f);
      lnred[tid][0] = make_float2(mu, rstd);
    }
    __syncthreads();
    float g = ln2G[col], bb = ln2B[col];
#pragma unroll
    for (int m = 0; m < 4; ++m)
#pragma unroll
      for (int j = 0; j < 4; ++j) {
        float2 st = lnred[m * 16 + rb + j][0];
        Hs[m * 16 + rb + j][col] = f2bf((yreg[m][j] - st.x) * st.y * g + bb);
      }
  }
  __syncthreads();
  f32x4 acc2[4] = {};
#pragma unroll
  for (int c = 0; c < 4; ++c) {
    bf16x8 w1n[4], w2n[4];
    if (c < 3) {
#pragma unroll
      for (int kt = 0; kt < 4; ++kt) {
        w1n[kt] = *(const bf16x8*)(W1_ + (size_t)((c + 1) * 128 + col) * 128 + kt * 32 + lk);
        w2n[kt] = *(const bf16x8*)(W2_ + (size_t)col * 512 + (c + 1) * 128 + kt * 32 + lk);
      }
    }
    f32x4 accm[4] = {};
#pragma unroll
    for (int kt = 0; kt < 4; ++kt)
#pragma unroll
      for (int m = 0; m < 4; ++m) {
        bf16x8 a = *(const bf16x8*)&Hs[m * 16 + lr][kt * 32 + lk];
        accm[m] = __builtin_amdgcn_mfma_f32_16x16x32_bf16(a, w1f[kt], accm[m], 0, 0, 0);
      }
    float b1v = Bl[512 + c * 128 + col];
#pragma unroll
    for (int m = 0; m < 4; ++m)
#pragma unroll
      for (int j = 0; j < 4; ++j)
        Mid[m * 16 + rb + j][col] = f2bf(fmaxf(accm[m][j] + b1v, 0.f));
    __syncthreads();
#pragma unroll
    for (int kt = 0; kt < 4; ++kt)
#pragma unroll
      for (int m = 0; m < 4; ++m) {
        bf16x8 a = *(const bf16x8*)&Mid[m * 16 + lr][kt * 32 + lk];
        acc2[m] = __builtin_amdgcn_mfma_f32_16x16x32_bf16(a, w2f[kt], acc2[m], 0, 0, 0);
      }
    __syncthreads();
    if (c < 3) {
#pragma unroll
      for (int kt = 0; kt < 4; ++kt) { w1f[kt] = w1n[kt]; w2f[kt] = w2n[kt]; }
    }
  }
  float vfin[4][4];
  {
    float bval = Bl[1024 + col];
    float s[4][4], sq[4][4];
#pragma unroll
    for (int m = 0; m < 4; ++m)
#pragma unroll
      for (int j = 0; j < 4; ++j) {
        float v = acc2[m][j] + bval + yreg[m][j];
        vfin[m][j] = v;
        s[m][j] = v;
        sq[m][j] = v * v;
      }
#pragma unroll
    for (int off = 1; off < 16; off <<= 1)
#pragma unroll
      for (int m = 0; m < 4; ++m)
#pragma unroll
        for (int j = 0; j < 4; ++j) {
          s[m][j] += __shfl_xor(s[m][j], off);
          sq[m][j] += __shfl_xor(sq[m][j], off);
        }
    if (lr == 0)
#pragma unroll
      for (int m = 0; m < 4; ++m)
#pragma unroll
        for (int j = 0; j < 4; ++j)
          lnred[m * 16 + rb + j][w] = make_float2(s[m][j], sq[m][j]);
    __syncthreads();
    if (tid < 64) {
      float ts = 0.f, tq = 0.f;
#pragma unroll
      for (int k = 0; k < 8; ++k) { float2 p = lnred[tid][k]; ts += p.x; tq += p.y; }
      float mu = ts * (1.0f / 128.0f);
      float rstd = rsqrtf(tq * (1.0f / 128.0f) - mu * mu + 1e-6f);
      lnred[tid][0] = make_float2(mu, rstd);
    }
    __syncthreads();
    float g = lnxG[col], bb = lnxB[col];
#pragma unroll
    for (int m = 0; m < 4; ++m)
#pragma unroll
      for (int j = 0; j < 4; ++j) {
        int row = r0 + m * 16 + rb + j;
        float2 st = lnred[m * 16 + rb + j][0];
        float t = (vfin[m][j] - st.x) * st.y * g + bb;
        if (finalMode == 0) {
          Yout[(size_t)row * 128 + col] = vfin[m][j];
          AbOut[(size_t)row * 128 + col] = f2bf(t);
        } else {
          Yout[(size_t)row * 128 + col] = t;
        }
      }
  }
}

// ---- context attention v4: single fused pass, bf16 LDS (stride 128, chunk XOR swizzle).
//      p[l]=exp(s[l]*scale) is independent per l -> read each window row ONCE. ----
__global__ __launch_bounds__(128) void ctx_kernel(
    const unsigned short* __restrict__ qin, const unsigned short* __restrict__ kin,
    unsigned short* __restrict__ cqo, unsigned short* __restrict__ cko) {
  __shared__ unsigned short xs[47 * 128];
  const unsigned short* src = blockIdx.y ? kin : qin;
  unsigned short* dst = blockIdx.y ? cko : cqo;
  const size_t rbase = (size_t)blockIdx.x * 256;
  const int t0 = blockIdx.z * 32;
  const int tid = threadIdx.x;
  // stage 47 rows (t0-15 .. t0+31) as raw bf16; chunk cj stored at cj ^ (row & 15)
#pragma unroll
  for (int it = 0; it < 6; ++it) {
    int idx = it * 128 + tid;
    int i = idx >> 4, cj = idx & 15;
    if (i < 47) {
      int rg = t0 - 15 + i;
      ushortx8 wv = {};
      if (rg >= 0) wv = *(const ushortx8*)(src + (rbase + rg) * 128 + cj * 8);
      int cp = cj ^ (i & 15);
      *(ushortx8*)&xs[i * 128 + cp * 8] = wv;
    }
  }
  __syncthreads();
  const int ql = tid >> 2, qu = tid & 3;  // 4 lanes per query, cols qu*32..+32
  // own row fp32 in registers
  float ow[32];
  {
    int r = ql + 15;
#pragma unroll
    for (int j = 0; j < 4; ++j) {
      int cp = (qu * 4 + j) ^ (r & 15);
      ushortx8 v = *(const ushortx8*)&xs[r * 128 + cp * 8];
#pragma unroll
      for (int jj = 0; jj < 8; ++jj) ow[j * 8 + jj] = bf2f(v[jj]);
    }
  }
  float den = 0.f;
  float o[32];
#pragma unroll
  for (int c = 0; c < 32; ++c) o[c] = 0.f;
#pragma unroll
  for (int l = 0; l < 16; ++l) {
    int r = ql + l;
    ushortx8 vc0, vc1, vc2, vc3;
    {
      int cp0 = (qu * 4 + 0) ^ (r & 15);
      int cp1 = (qu * 4 + 1) ^ (r & 15);
      int cp2 = (qu * 4 + 2) ^ (r & 15);
      int cp3 = (qu * 4 + 3) ^ (r & 15);
      vc0 = *(const ushortx8*)&xs[r * 128 + cp0 * 8];
      vc1 = *(const ushortx8*)&xs[r * 128 + cp1 * 8];
      vc2 = *(const ushortx8*)&xs[r * 128 + cp2 * 8];
      vc3 = *(const ushortx8*)&xs[r * 128 + cp3 * 8];
    }
    float d = 0.f;
#pragma unroll
    for (int jj = 0; jj < 8; ++jj) {
      d = fmaf(ow[jj],      bf2f(vc0[jj]), d);
      d = fmaf(ow[8 + jj],  bf2f(vc1[jj]), d);
      d = fmaf(ow[16 + jj], bf2f(vc2[jj]), d);
      d = fmaf(ow[24 + jj], bf2f(vc3[jj]), d);
    }
    float sc = d + __shfl_xor(d, 1);   // full 128-dot across the 4-lane group
    sc += __shfl_xor(sc, 2);
    float p = __expf(sc * 0.08838834764831845f);  // pad rows: dot=0 -> exp(0)=1
    den += p;
#pragma unroll
    for (int jj = 0; jj < 8; ++jj) {
      o[jj]      = fmaf(p, bf2f(vc0[jj]), o[jj]);
      o[8 + jj]  = fmaf(p, bf2f(vc1[jj]), o[8 + jj]);
      o[16 + jj] = fmaf(p, bf2f(vc2[jj]), o[16 + jj]);
      o[24 + jj] = fmaf(p, bf2f(vc3[jj]), o[24 + jj]);
    }
  }
  float inv = 1.0f / den;
  unsigned short* op = dst + (rbase + t0 + ql) * 128 + qu * 32;
#pragma unroll
  for (int c8 = 0; c8 < 4; ++c8) {
    ushortx8 rr;
#pragma unroll
    for (int j = 0; j < 8; ++j) rr[j] = f2bf(o[c8 * 8 + j] * inv);
    *(ushortx8*)(op + c8 * 8) = rr;
  }
}

// ---- attn1 (MFMA): S^T = CK·CQ^T (32x32x16); P via LDS; O = P·V (16x16x32) ----
static constexpr int PW = 272;
__global__ __launch_bounds__(256) void attn1_kernel(
    const unsigned short* __restrict__ cq, const unsigned short* __restrict__ ck,
    unsigned short* v) {
  __shared__ unsigned short vt[16][PW];
  __shared__ unsigned short ps[4][32][PW];
  __shared__ float rsum[4][32];
  const int bm = blockIdx.x >> 3, h = blockIdx.x & 7;
  const size_t rbase = (size_t)bm * 256;
  const int cbase = h * 16;
  const int tid = threadIdx.x;
  {
    ushortx8 v0 = *(const ushortx8*)(v + (rbase + tid) * 128 + cbase);
    ushortx8 v1 = *(const ushortx8*)(v + (rbase + tid) * 128 + cbase + 8);
#pragma unroll
    for (int d = 0; d < 8; ++d) { vt[d][tid] = v0[d]; vt[8 + d][tid] = v1[d]; }
  }
  __syncthreads();
  const int wid = tid >> 6, lane = tid & 63;
  const int l31 = lane & 31, l15 = lane & 15;
  const int hi5 = lane >> 5, hi4 = lane >> 4;
#pragma unroll
  for (int qt = 0; qt < 2; ++qt) {
    const int q0 = (wid * 2 + qt) * 32;
    bf16x8 bq = *(const bf16x8*)(cq + (rbase + q0 + l31) * 128 + cbase + hi5 * 8);
    float lsum = 0.f;
#pragma unroll
    for (int kt = 0; kt < 8; ++kt) {
      bf16x8 ak = *(const bf16x8*)(ck + (rbase + kt * 32 + l31) * 128 + cbase + hi5 * 8);
      f32x16 z = {};
      f32x16 s = __builtin_amdgcn_mfma_f32_32x32x16_bf16(ak, bq, z, 0, 0, 0);
      float p[16];
#pragma unroll
      for (int r = 0; r < 16; ++r) { p[r] = __expf(s[r] * 0.25f); lsum += p[r]; }
#pragma unroll
      for (int r = 0; r < 16; r += 2) {
        unsigned int pk = cvt_pk_bf16(p[r], p[r + 1]);
        int key = kt * 32 + (r & 3) + 8 * (r >> 2) + 4 * hi5;
        *(unsigned int*)&ps[wid][l31][key] = pk;
      }
    }
    lsum += __shfl_xor(lsum, 32);
    if (lane < 32) rsum[wid][lane] = 1.0f / lsum;
#pragma unroll
    for (int m = 0; m < 2; ++m) {
      f32x4 o = {};
#pragma unroll
      for (int k2 = 0; k2 < 8; ++k2) {
        bf16x8 pa = *(const bf16x8*)&ps[wid][m * 16 + l15][k2 * 32 + hi4 * 8];
        bf16x8 vb = *(const bf16x8*)&vt[l15][k2 * 32 + hi4 * 8];
        o = __builtin_amdgcn_mfma_f32_16x16x32_bf16(pa, vb, o, 0, 0, 0);
      }
      unsigned short* dst = v + (rbase + q0 + m * 16 + hi4 * 4) * 128 + cbase + l15;
#pragma unroll
      for (int j = 0; j < 4; ++j) {
        float inv = rsum[wid][m * 16 + hi4 * 4 + j];
        dst[(size_t)j * 128] = f2bf(o[j] * inv);
      }
    }
  }
}

// ---- attn2 over M=16 axis (bf16 in/out); scrambled write g=q*4+b ----
__global__ __launch_bounds__(128) void attn2_kernel(
    const unsigned short* __restrict__ xa, unsigned short* __restrict__ xr) {
  __shared__ float xas[16][128];
  int b = blockIdx.x >> 8, t = blockIdx.x & 255;
  int tid = threadIdx.x;
#pragma unroll
  for (int jj = 0; jj < 2; ++jj) {
    int idx = tid + (jj << 7);
    int r = idx >> 4, c8 = (idx & 15) * 8;
    ushortx8 vv = *(const ushortx8*)(xa + ((size_t)((b * 16 + r) * 256 + t)) * 128 + c8);
#pragma unroll
    for (int j = 0; j < 8; ++j) xas[r][c8 + j] = bf2f(vv[j]);
  }
  __syncthreads();
  int h = tid >> 4, q = tid & 15;
  float xq[16];
#pragma unroll
  for (int d = 0; d < 16; d++) xq[d] = xas[q][h * 16 + d];
  float sc[16];
  float mx = -1e30f;
#pragma unroll
  for (int k = 0; k < 16; k++) {
    float s = 0.f;
#pragma unroll
    for (int d = 0; d < 16; d++) s += xq[d] * xas[k][h * 16 + d];
    s *= 0.25f;
    sc[k] = s;
    mx = fmaxf(mx, s);
  }
  float den = 0.f;
#pragma unroll
  for (int k = 0; k < 16; k++) { sc[k] = __expf(sc[k] - mx); den += sc[k]; }
  float inv = 1.0f / den;
  float out[16] = {};
#pragma unroll
  for (int k = 0; k < 16; k++) {
    float w = sc[k];
#pragma unroll
    for (int d = 0; d < 16; d++) out[d] += w * xas[k][h * 16 + d];
  }
  int g = q * 4 + b;
  unsigned short* dstp = xr + ((size_t)(g * 256 + t)) * 128 + h * 16;
  ushortx8 r0;
#pragma unroll
  for (int j = 0; j < 8; ++j) r0[j] = f2bf(out[j] * inv);
  *(ushortx8*)dstp = r0;
#pragma unroll
  for (int j = 0; j < 8; ++j) r0[j] = f2bf(out[8 + j] * inv);
  *(ushortx8*)(dstp + 8) = r0;
}

extern "C" void kernel_launch(void* const* d_in, const int* in_sizes, int n_in,
                              void* d_out, int out_size, void* d_ws, size_t ws_size,
                              hipStream_t stream) {
  const float* x    = (const float*)d_in[0];
  const float* Wq   = (const float*)d_in[1];
  const float* bq   = (const float*)d_in[2];
  const float* Wk   = (const float*)d_in[3];
  const float* bk   = (const float*)d_in[4];
  const float* Wv   = (const float*)d_in[5];
  const float* bv   = (const float*)d_in[6];
  const float* Wo   = (const float*)d_in[7];
  const float* bo   = (const float*)d_in[8];
  const float* W1   = (const float*)d_in[9];
  const float* b1   = (const float*)d_in[10];
  const float* W2   = (const float*)d_in[11];
  const float* b2   = (const float*)d_in[12];
  const float* ln1g = (const float*)d_in[13];
  const float* ln1b = (const float*)d_in[14];
  const float* ln2g = (const float*)d_in[15];
  const float* ln2b = (const float*)d_in[16];
  const float* lnfg = (const float*)d_in[17];
  const float* lnfb = (const float*)d_in[18];

  char* base = (char*)d_ws;
  unsigned short* CQb = (unsigned short*)base;                 // [0,4M)  ctx-out / layer-1 LN1 act
  unsigned short* CKb = (unsigned short*)(base + (4u  << 20)); // [4,8)
  unsigned short* Qb  = (unsigned short*)(base + (8u  << 20)); // [8,12)  Q|K|V contiguous
  unsigned short* Kb  = (unsigned short*)(base + (12u << 20)); // [12,16)
  unsigned short* Vb  = (unsigned short*)(base + (16u << 20)); // [16,20)
  unsigned short* Ab  = (unsigned short*)(base + (20u << 20)); // [20,24)
  unsigned short* Wb  = (unsigned short*)(base + (24u << 20)); // 768 KB
  float*          Bs  = (float*)(base + (24u << 20) + 786432); // 9.2 KB
  float*          Y   = (float*)d_out;

  prep_kernel<<<4297, 256, 0, stream>>>(x, Wq, Wk, Wv, Wo, W1, W2,
                                        bq, bk, bv, bo, b1, b2,
                                        ln1g, ln1b, Wb, Bs, Ab);

  for (int i = 0; i < 2; ++i) {
    const float* rin = i ? Y : x;
    const unsigned short* Wl = Wb + (size_t)i * 196608;
    const float* Bl = Bs + i * 1152;
    const unsigned short* Acur = (i == 0) ? Ab : CQb;
    gemm_kernel<3, 1><<<1024, 512, 0, stream>>>(Acur, 128, Wl, 128, Bl, Qb, 128);
    ctx_kernel<<<dim3(64, 2, 8), 128, 0, stream>>>(Qb, Kb, CQb, CKb);
    attn1_kernel<<<512, 256, 0, stream>>>(CQb, CKb, Vb);
    attn2_kernel<<<1024, 128, 0, stream>>>(Vb, Ab);
    if (i == 0) {
      ffn_kernel<<<256, 512, 0, stream>>>(Ab, Wl + 49152, Wl + 65536, Wl + 131072, Bl,
          rin, ln2g, ln2b, ln1g + 128, ln1b + 128, Y, CQb, 0);
    } else {
      ffn_kernel<<<256, 512, 0, stream>>>(Ab, Wl + 49152, Wl + 65536, Wl + 131072, Bl,
          rin, ln2g + 128, ln2b + 128, lnfg, lnfb, Y, nullptr, 1);
    }
  }
}